// Round 3
// baseline (104.730 us; speedup 1.0000x reference)
//
#include <hip/hip_runtime.h>
#include <hip/hip_bf16.h>

// Problem: B=512, D=256, M=256, TEMP=0.07
//   anchor = features_o[mask_sents]            [M,D]
//   sim    = anchor @ features_i^T / TEMP      [M,B]
//   loss_sum = sum_m sum_{p in pos(m)} sum_{n in neg(m)} softplus(sim[m,n]-sim[m,p])
//   pair_num = sum_m |pos(m)|*|neg(m)|
//   loss = pair_num>0 ? loss_sum/pair_num : loss_sum
//
// Structure: tiny tiled GEMM (sim, pre-scaled by 1/TEMP*log2e) -> ws,
// then 1024-block pair kernel (4 blocks/row, p-tiles split by residue),
// 4x4 register tiling on float4 LDS reads, log2-space softplus,
// last-block-ticket finalize.
//
// ws layout: [0] float loss_sum, [1] uint pair_num, [2] uint ticket,
//            +256B float sim[M*B] (512 KB, scaled).

#define BDIM 512
#define MDIM 256
#define DDIM 256
#define LOG2E 1.44269504088896340736f
#define LN2   0.69314718055994530942f
#define SIM_SCALE ((1.0f / 0.07f) * LOG2E)

// ---------------- Kernel 1: sim = (fo[sents] @ fi^T) * SIM_SCALE -------------
__global__ __launch_bounds__(256) void sim_kernel(
        const float* __restrict__ fo, const float* __restrict__ fi,
        const int* __restrict__ sents, float* __restrict__ sim) {
    __shared__ float As[32][33];
    __shared__ float Bs[32][33];
    __shared__ int rowIdx[32];
    const int tid = threadIdx.x;
    const int m0 = blockIdx.y * 32;
    const int n0 = blockIdx.x * 32;
    if (tid < 32) rowIdx[tid] = sents[m0 + tid];
    __syncthreads();
    const int tx = tid & 15, ty = tid >> 4;
    float a00 = 0.f, a01 = 0.f, a10 = 0.f, a11 = 0.f;
    for (int k0 = 0; k0 < DDIM; k0 += 32) {
#pragma unroll
        for (int i = 0; i < 4; ++i) {
            int idx = tid + i * 256;
            int r = idx >> 5, c = idx & 31;
            As[r][c] = fo[rowIdx[r] * DDIM + k0 + c];
            Bs[r][c] = fi[(n0 + r) * DDIM + k0 + c];
        }
        __syncthreads();
#pragma unroll
        for (int k = 0; k < 32; ++k) {
            float av0 = As[ty][k],     av1 = As[ty + 16][k];
            float bv0 = Bs[tx][k],     bv1 = Bs[tx + 16][k];
            a00 = fmaf(av0, bv0, a00);
            a01 = fmaf(av0, bv1, a01);
            a10 = fmaf(av1, bv0, a10);
            a11 = fmaf(av1, bv1, a11);
        }
        __syncthreads();
    }
    sim[(m0 + ty) * BDIM + n0 + tx]           = a00 * SIM_SCALE;
    sim[(m0 + ty) * BDIM + n0 + tx + 16]      = a01 * SIM_SCALE;
    sim[(m0 + ty + 16) * BDIM + n0 + tx]      = a10 * SIM_SCALE;
    sim[(m0 + ty + 16) * BDIM + n0 + tx + 16] = a11 * SIM_SCALE;
}

// ---------------- Kernel 2: pairwise softplus loss ---------------------------
// 4 blocks per row m (p-tiles interleaved by residue mod 64), 512 threads as
// 32(n-tiles) x 16(p-tiles), each iteration = 4x4 pairs from two float4 reads.
__global__ __launch_bounds__(512) void loss_kernel(
        const float* __restrict__ sim, const float* __restrict__ mask,
        const int* __restrict__ sents, float* __restrict__ ws,
        float* __restrict__ out, int nblocks) {
    __shared__ float4 s_psim4[130];   // 516+ floats (sentinel padding)
    __shared__ float4 s_nsim4[130];
    __shared__ int   s_wcnt[8];
    __shared__ float s_red[8];
    float* s_psim = (float*)s_psim4;
    float* s_nsim = (float*)s_nsim4;

    const int tid  = threadIdx.x;
    const int lane = tid & 63;
    const int wave = tid >> 6;
    const int m    = blockIdx.x >> 2;
    const int pblk = blockIdx.x & 3;
    const int srow = sents[m];

    const float simval = sim[m * BDIM + tid];        // pre-scaled
    const float mv     = mask[srow * BDIM + tid];
    const bool flag = (mv > 0.5f);

    // deterministic ballot-based compaction (identical across sibling blocks)
    unsigned long long bal = __ballot(flag);
    int below = __popcll(bal & ((1ull << lane) - 1ull));
    if (lane == 0) s_wcnt[wave] = __popcll(bal);
    __syncthreads();
    int base_pos = 0, np = 0;
#pragma unroll
    for (int w = 0; w < 8; ++w) {
        int c = s_wcnt[w];
        if (w < wave) base_pos += c;
        np += c;
    }
    const int nn = BDIM - np;
    const int base_neg = wave * 64 - base_pos;
    if (flag) s_psim[base_pos + below]          = simval;
    else      s_nsim[base_neg + (lane - below)] = simval;
    if (tid < 4) {                                   // zero-contribution pads
        s_psim[np + tid] =  __builtin_inff();
        s_nsim[nn + tid] = -__builtin_inff();
    }
    __syncthreads();

    // pair loop over 4x4 tiles, log2-space softplus:
    //   contrib = max(t,0) + log2(1 + 2^{-|t|}),  t = sn - sp   (ln2-scaled later)
    const int tn = tid & 31;           // n-tile index
    const int tp = tid >> 5;           // 0..15 p-tile slot within block
    const int p_t4 = (np + 3) >> 2;
    const int n_t4 = (nn + 3) >> 2;
    float lsum = 0.f;
    for (int ip = pblk * 16 + tp; ip < p_t4; ip += 64) {
        const float4 P = s_psim4[ip];
        for (int in = tn; in < n_t4; in += 32) {
            const float4 Nv = s_nsim4[in];
#define SPLUS(nv, pv)                                                     \
            {                                                             \
                float t = (nv) - (pv);                                    \
                float e = __builtin_amdgcn_exp2f(-__builtin_fabsf(t));    \
                lsum += fmaxf(t, 0.f) + __builtin_amdgcn_logf(1.f + e);   \
            }
            SPLUS(Nv.x, P.x) SPLUS(Nv.x, P.y) SPLUS(Nv.x, P.z) SPLUS(Nv.x, P.w)
            SPLUS(Nv.y, P.x) SPLUS(Nv.y, P.y) SPLUS(Nv.y, P.z) SPLUS(Nv.y, P.w)
            SPLUS(Nv.z, P.x) SPLUS(Nv.z, P.y) SPLUS(Nv.z, P.z) SPLUS(Nv.z, P.w)
            SPLUS(Nv.w, P.x) SPLUS(Nv.w, P.y) SPLUS(Nv.w, P.z) SPLUS(Nv.w, P.w)
#undef SPLUS
        }
    }

    // block reduction + global accumulate
#pragma unroll
    for (int off = 32; off > 0; off >>= 1) lsum += __shfl_down(lsum, off);
    if (lane == 0) s_red[wave] = lsum;
    __syncthreads();
    if (tid == 0) {
        float bs = 0.f;
#pragma unroll
        for (int w = 0; w < 8; ++w) bs += s_red[w];
        atomicAdd(&ws[0], bs * LN2);
        if (pblk == 0) atomicAdd((unsigned int*)ws + 1, (unsigned int)(np * nn));
        __threadfence();
        unsigned int old = atomicAdd((unsigned int*)ws + 2, 1u);
        if (old == (unsigned int)(nblocks - 1)) {
            __threadfence();
            float ls = __hip_atomic_load(&ws[0], __ATOMIC_RELAXED,
                                         __HIP_MEMORY_SCOPE_AGENT);
            unsigned int pn = __hip_atomic_load((unsigned int*)ws + 1,
                                                __ATOMIC_RELAXED,
                                                __HIP_MEMORY_SCOPE_AGENT);
            out[0] = (pn > 0u) ? (ls / (float)pn) : ls;
        }
    }
}

extern "C" void kernel_launch(void* const* d_in, const int* in_sizes, int n_in,
                              void* d_out, int out_size, void* d_ws, size_t ws_size,
                              hipStream_t stream) {
    const float* fo    = (const float*)d_in[0];   // [512,256]
    const float* fi    = (const float*)d_in[1];   // [512,256]
    const float* mask  = (const float*)d_in[2];   // [512,512]
    const int*   sents = (const int*)d_in[3];     // [256]
    float* out = (float*)d_out;
    float* ws  = (float*)d_ws;
    float* sim = (float*)((char*)d_ws + 256);

    hipMemsetAsync(d_ws, 0, 12, stream);

    dim3 grid1(BDIM / 32, MDIM / 32);             // (16, 8)
    sim_kernel<<<grid1, 256, 0, stream>>>(fo, fi, sents, sim);

    const int nblocks = 4 * MDIM;                 // 1024
    loss_kernel<<<nblocks, BDIM, 0, stream>>>(sim, mask, sents, ws, out, nblocks);
}

// Round 4
// 82.904 us; speedup vs baseline: 1.2633x; 1.2633x over previous
//
#include <hip/hip_runtime.h>
#include <hip/hip_bf16.h>

// Problem: B=512, D=256, M=256, TEMP=0.07
//   anchor = features_o[mask_sents]            [M,D]
//   sim    = anchor @ features_i^T / TEMP      [M,B]
//   loss_sum = sum_m sum_{p in pos(m)} sum_{n in neg(m)} softplus(sim[m,n]-sim[m,p])
//   pair_num = sum_m |pos(m)|*|neg(m)|
//   loss = pair_num>0 ? loss_sum/pair_num : loss_sum
//
// Structure (consolidated best-of R1/R3):
//   k1: tiled GEMM, sim pre-scaled by (1/TEMP)*log2e  -> ws
//   k2: 1024 blocks (4 siblings/row, p-tiles by residue), 4x4 float4 register
//       tiling, log2-space stable softplus, partials scattered over 64 slots
//       (no same-address atomic pileup, no threadfence/ticket)
//   k3: 64-thread finalize wave-reduces slots, writes out.
//
// ws layout: float ws[0..63]  loss partial slots
//            uint  ws[64..127] pair_num partial slots   (memset 512 B)
//            +1KB  float sim[M*B] (512 KB, scaled)

#define BDIM 512
#define MDIM 256
#define DDIM 256
#define LOG2E 1.44269504088896340736f
#define LN2   0.69314718055994530942f
#define SIM_SCALE ((1.0f / 0.07f) * LOG2E)
#define NSLOT 64

// ---------------- Kernel 1: sim = (fo[sents] @ fi^T) * SIM_SCALE -------------
__global__ __launch_bounds__(256) void sim_kernel(
        const float* __restrict__ fo, const float* __restrict__ fi,
        const int* __restrict__ sents, float* __restrict__ sim) {
    __shared__ float As[32][33];
    __shared__ float Bs[32][33];
    __shared__ int rowIdx[32];
    const int tid = threadIdx.x;
    const int m0 = blockIdx.y * 32;
    const int n0 = blockIdx.x * 32;
    if (tid < 32) rowIdx[tid] = sents[m0 + tid];
    __syncthreads();
    const int tx = tid & 15, ty = tid >> 4;
    float a00 = 0.f, a01 = 0.f, a10 = 0.f, a11 = 0.f;
    for (int k0 = 0; k0 < DDIM; k0 += 32) {
#pragma unroll
        for (int i = 0; i < 4; ++i) {
            int idx = tid + i * 256;
            int r = idx >> 5, c = idx & 31;
            As[r][c] = fo[rowIdx[r] * DDIM + k0 + c];
            Bs[r][c] = fi[(n0 + r) * DDIM + k0 + c];
        }
        __syncthreads();
#pragma unroll
        for (int k = 0; k < 32; ++k) {
            float av0 = As[ty][k],     av1 = As[ty + 16][k];
            float bv0 = Bs[tx][k],     bv1 = Bs[tx + 16][k];
            a00 = fmaf(av0, bv0, a00);
            a01 = fmaf(av0, bv1, a01);
            a10 = fmaf(av1, bv0, a10);
            a11 = fmaf(av1, bv1, a11);
        }
        __syncthreads();
    }
    sim[(m0 + ty) * BDIM + n0 + tx]           = a00 * SIM_SCALE;
    sim[(m0 + ty) * BDIM + n0 + tx + 16]      = a01 * SIM_SCALE;
    sim[(m0 + ty + 16) * BDIM + n0 + tx]      = a10 * SIM_SCALE;
    sim[(m0 + ty + 16) * BDIM + n0 + tx + 16] = a11 * SIM_SCALE;
}

// ---------------- Kernel 2: pairwise softplus loss ---------------------------
__global__ __launch_bounds__(512) void loss_kernel(
        const float* __restrict__ sim, const float* __restrict__ mask,
        const int* __restrict__ sents, float* __restrict__ ws) {
    __shared__ float4 s_psim4[130];   // 516+ floats (sentinel padding)
    __shared__ float4 s_nsim4[130];
    __shared__ int   s_wcnt[8];
    __shared__ float s_red[8];
    float* s_psim = (float*)s_psim4;
    float* s_nsim = (float*)s_nsim4;

    const int tid  = threadIdx.x;
    const int lane = tid & 63;
    const int wave = tid >> 6;
    const int m    = blockIdx.x >> 2;
    const int pblk = blockIdx.x & 3;
    const int srow = sents[m];

    const float simval = sim[m * BDIM + tid];        // pre-scaled by SIM_SCALE
    const float mv     = mask[srow * BDIM + tid];
    const bool flag = (mv > 0.5f);

    // deterministic ballot-based compaction (identical across sibling blocks)
    unsigned long long bal = __ballot(flag);
    int below = __popcll(bal & ((1ull << lane) - 1ull));
    if (lane == 0) s_wcnt[wave] = __popcll(bal);
    __syncthreads();
    int base_pos = 0, np = 0;
#pragma unroll
    for (int w = 0; w < 8; ++w) {
        int c = s_wcnt[w];
        if (w < wave) base_pos += c;
        np += c;
    }
    const int nn = BDIM - np;
    const int base_neg = wave * 64 - base_pos;
    if (flag) s_psim[base_pos + below]          = simval;
    else      s_nsim[base_neg + (lane - below)] = simval;
    if (tid < 4) {                                   // zero-contribution pads
        s_psim[np + tid] =  __builtin_inff();
        s_nsim[nn + tid] = -__builtin_inff();
    }
    __syncthreads();

    // pair loop over 4x4 tiles in log2 space:
    //   contrib = max(t,0) + log2(1 + 2^{-|t|}),  t = sn - sp  (x LN2 at the end)
    const int tn = tid & 31;           // n-tile index
    const int tp = tid >> 5;           // p-tile slot within block (0..15)
    const int p_t4 = (np + 3) >> 2;
    const int n_t4 = (nn + 3) >> 2;
    float lsum = 0.f;
    for (int ip = pblk * 16 + tp; ip < p_t4; ip += 64) {
        const float4 P = s_psim4[ip];
        for (int in = tn; in < n_t4; in += 32) {
            const float4 Nv = s_nsim4[in];
#define SPLUS(nv, pv)                                                     \
            {                                                             \
                float t = (nv) - (pv);                                    \
                float e = __builtin_amdgcn_exp2f(-__builtin_fabsf(t));    \
                lsum += fmaxf(t, 0.f) + __builtin_amdgcn_logf(1.f + e);   \
            }
            SPLUS(Nv.x, P.x) SPLUS(Nv.x, P.y) SPLUS(Nv.x, P.z) SPLUS(Nv.x, P.w)
            SPLUS(Nv.y, P.x) SPLUS(Nv.y, P.y) SPLUS(Nv.y, P.z) SPLUS(Nv.y, P.w)
            SPLUS(Nv.z, P.x) SPLUS(Nv.z, P.y) SPLUS(Nv.z, P.z) SPLUS(Nv.z, P.w)
            SPLUS(Nv.w, P.x) SPLUS(Nv.w, P.y) SPLUS(Nv.w, P.z) SPLUS(Nv.w, P.w)
#undef SPLUS
        }
    }

    // block reduction, then scatter partials across 64 slots
#pragma unroll
    for (int off = 32; off > 0; off >>= 1) lsum += __shfl_down(lsum, off);
    if (lane == 0) s_red[wave] = lsum;
    __syncthreads();
    if (tid == 0) {
        float bs = 0.f;
#pragma unroll
        for (int w = 0; w < 8; ++w) bs += s_red[w];
        const int slot = blockIdx.x & (NSLOT - 1);
        atomicAdd(&ws[slot], bs * LN2);
        if (pblk == 0)
            atomicAdd((unsigned int*)ws + NSLOT + (m & (NSLOT - 1)),
                      (unsigned int)(np * nn));
    }
}

// ---------------- Kernel 3: finalize -----------------------------------------
__global__ __launch_bounds__(64) void finalize_kernel(
        const float* __restrict__ ws, float* __restrict__ out) {
    const int t = threadIdx.x;
    float ls = ws[t];
    float pn = (float)((const unsigned int*)ws)[NSLOT + t];
#pragma unroll
    for (int off = 32; off > 0; off >>= 1) {
        ls += __shfl_down(ls, off);
        pn += __shfl_down(pn, off);
    }
    if (t == 0) out[0] = (pn > 0.f) ? (ls / pn) : ls;
}

extern "C" void kernel_launch(void* const* d_in, const int* in_sizes, int n_in,
                              void* d_out, int out_size, void* d_ws, size_t ws_size,
                              hipStream_t stream) {
    const float* fo    = (const float*)d_in[0];   // [512,256]
    const float* fi    = (const float*)d_in[1];   // [512,256]
    const float* mask  = (const float*)d_in[2];   // [512,512]
    const int*   sents = (const int*)d_in[3];     // [256]
    float* out = (float*)d_out;
    float* ws  = (float*)d_ws;
    float* sim = (float*)((char*)d_ws + 1024);

    hipMemsetAsync(d_ws, 0, 2 * NSLOT * 4, stream);   // zero 128 slots

    dim3 grid1(BDIM / 32, MDIM / 32);             // (16, 8)
    sim_kernel<<<grid1, 256, 0, stream>>>(fo, fi, sents, sim);

    loss_kernel<<<4 * MDIM, BDIM, 0, stream>>>(sim, mask, sents, ws);

    finalize_kernel<<<1, 64, 0, stream>>>(ws, out);
}